// Round 1
// baseline (541.745 us; speedup 1.0000x reference)
//
#include <hip/hip_runtime.h>
#include <hip/hip_bf16.h>
#include <stdint.h>

typedef __attribute__((ext_vector_type(8))) __bf16 bf16x8;
typedef __attribute__((ext_vector_type(4))) float floatx4;

#define C 128
#define BROWS 64
#define LSTR 136   // padded bf16 row stride: 272 B = 17*16 B (odd multiple of 16 B -> even bank-quad spread)

__device__ __forceinline__ __bf16 f2b(float f) {
  return __builtin_bit_cast(__bf16, __float2bfloat16(f));
}

__global__ void zero_kernel(int* __restrict__ p, int n) {
  int i = blockIdx.x * blockDim.x + threadIdx.x;
  if (i < n) p[i] = 0;
}

// histogram of row indices + W fp32 -> bf16 conversion
__global__ void prep_kernel(const int* __restrict__ rowidx, const float* __restrict__ W,
                            int* __restrict__ deg, __bf16* __restrict__ Wb, int n) {
  int i = blockIdx.x * blockDim.x + threadIdx.x;
  if (i < C * C) Wb[i] = f2b(W[i]);
  if (i < n) atomicAdd(deg + rowidx[i], 1);
}

// result[j] = (x[j] + x[col[j]]) @ W.T + 2*b + deg[j]
__launch_bounds__(256, 3)
__global__ void gconv_kernel(const float* __restrict__ x,
                             const int* __restrict__ colidx,
                             const __bf16* __restrict__ Wb,
                             const float* __restrict__ bias,
                             const int* __restrict__ deg,
                             float* __restrict__ out, int n) {
  __shared__ __bf16 sIn[BROWS * LSTR];   // 17408 B
  __shared__ __bf16 sW[C * LSTR];        // 34816 B
  __shared__ float sDeg[BROWS];          // -> 52.5 KB total => 3 blocks/CU

  const int t = threadIdx.x;
  const int base = blockIdx.x * BROWS;

  // ---- stage W (bf16, padded rows): thread t covers row t>>1, half t&1 (64 bf16 = 128 B) ----
  {
    int r = t >> 1, h = t & 1;
    const float4* src = (const float4*)(Wb + r * C + h * 64);
    float4* dst = (float4*)(sW + r * LSTR + h * 64);
#pragma unroll
    for (int i = 0; i < 8; i++) dst[i] = src[i];
  }
  // ---- stage deg as float ----
  if (t < BROWS) {
    int g = base + t;
    sDeg[t] = (g < n) ? (float)deg[g] : 0.0f;
  }
  // ---- stage x[g] + x[col[g]] as bf16: 4 threads per row, 32 cols each ----
  {
    int r = t >> 2, q = t & 3;
    int g = base + r;
    if (g < n) {
      int cg = colidx[g];
      const float4* p0 = (const float4*)(x + (size_t)g * C + q * 32);
      const float4* p1 = (const float4*)(x + (size_t)cg * C + q * 32);
      __bf16* drow = sIn + r * LSTR + q * 32;
#pragma unroll
      for (int i = 0; i < 4; i++) {
        float4 a0 = p0[2 * i], a1 = p0[2 * i + 1];
        float4 c0 = p1[2 * i], c1 = p1[2 * i + 1];
        bf16x8 u;
        u[0] = f2b(a0.x + c0.x); u[1] = f2b(a0.y + c0.y);
        u[2] = f2b(a0.z + c0.z); u[3] = f2b(a0.w + c0.w);
        u[4] = f2b(a1.x + c1.x); u[5] = f2b(a1.y + c1.y);
        u[6] = f2b(a1.z + c1.z); u[7] = f2b(a1.w + c1.w);
        *(bf16x8*)(drow + i * 8) = u;
      }
    }
  }
  __syncthreads();

  const int lane = t & 63, w = t >> 6;
  const int l15 = lane & 15, quad = lane >> 4;

  floatx4 acc[8];
#pragma unroll
  for (int i = 0; i < 8; i++) acc[i] = (floatx4){0.f, 0.f, 0.f, 0.f};

  // A[m=lane&15][k=quad*8+j]  (HW-verified layout, m120)
  const __bf16* aB = sIn + (w * 16 + l15) * LSTR + quad * 8;
  // B[k=quad*8+j][n=lane&15]; B = W^T so lane reads 8 consecutive k from W row n
  const __bf16* bB = sW + l15 * LSTR + quad * 8;

#pragma unroll
  for (int kc = 0; kc < 4; kc++) {
    bf16x8 av = *(const bf16x8*)(aB + kc * 32);
#pragma unroll
    for (int tt = 0; tt < 8; tt++) {
      bf16x8 bv = *(const bf16x8*)(bB + tt * 16 * LSTR + kc * 32);
      acc[tt] = __builtin_amdgcn_mfma_f32_16x16x32_bf16(av, bv, acc[tt], 0, 0, 0);
    }
  }

  // epilogue: C/D layout col=lane&15, row=quad*4+reg (HW-verified, m89/m91)
  float degv[4];
#pragma unroll
  for (int r = 0; r < 4; r++) degv[r] = sDeg[w * 16 + quad * 4 + r];

#pragma unroll
  for (int tt = 0; tt < 8; tt++) {
    int ncol = tt * 16 + l15;
    float b2 = 2.0f * bias[ncol];
#pragma unroll
    for (int r = 0; r < 4; r++) {
      int g = base + w * 16 + quad * 4 + r;
      if (g < n) out[(size_t)g * C + ncol] = acc[tt][r] + b2 + degv[r];
    }
  }
}

extern "C" void kernel_launch(void* const* d_in, const int* in_sizes, int n_in,
                              void* d_out, int out_size, void* d_ws, size_t ws_size,
                              hipStream_t stream) {
  const float* x    = (const float*)d_in[0];
  const int*   edge = (const int*)d_in[1];   // [2, n] flat: first n = row, next n = col
  const float* W    = (const float*)d_in[2];
  const float* bias = (const float*)d_in[3];
  float* out = (float*)d_out;

  const int n = in_sizes[0] / C;             // 500000

  int* deg = (int*)d_ws;
  size_t wb_off = ((size_t)n * sizeof(int) + 255) & ~(size_t)255;
  __bf16* Wb = (__bf16*)((char*)d_ws + wb_off);

  int nb = (n + 255) / 256;
  zero_kernel<<<nb, 256, 0, stream>>>(deg, n);
  prep_kernel<<<nb, 256, 0, stream>>>(edge, W, deg, Wb, n);

  int mb = (n + BROWS - 1) / BROWS;
  gconv_kernel<<<mb, 256, 0, stream>>>(x, edge + n, Wb, bias, deg, out, n);
}